// Round 1
// baseline (971.167 us; speedup 1.0000x reference)
//
#include <hip/hip_runtime.h>
#include <math.h>

#define GG 2000   // num_graphs (reference constant)

__device__ __forceinline__ int lower_bound_i(const int* __restrict__ b, int n, int v) {
    int lo = 0, hi = n;
    while (lo < hi) { int mid = (lo + hi) >> 1; if (b[mid] < v) lo = mid + 1; else hi = mid; }
    return lo;
}

// ---------------- Phase A: scores[n][o] = tanh(x@w1^T)@w2^T ----------------
// Block = 256 thr (4 waves). Per block-group: 64 nodes. Wave w handles nodes w*16..w*16+15.
// Lane l accumulates hidden dims l and l+64. K processed in 2 halves of 64, staged in LDS.
__global__ __launch_bounds__(256) void score_kernel(
    const float* __restrict__ x, const float* __restrict__ w1,
    const float* __restrict__ w2, float* __restrict__ scores,
    int n_nodes, int nbg)
{
    // LDS union: [w1s 128x68 | xs 64x68]  aliased by  [hs 64x132]
    __shared__ __align__(16) float lds[13056];           // 52224 B
    float* w1s = lds;                                    // 8704 floats
    float* xs  = lds + 8704;                             // 4352 floats
    float* hs  = lds;                                    // 8448 floats (alias)

    const int t = threadIdx.x;
    const int lane = t & 63;
    const int w = t >> 6;

    for (int bg = blockIdx.x; bg < nbg; bg += gridDim.x) {
        const int base = bg * 64;
        float acc0[16], acc1[16];
#pragma unroll
        for (int j = 0; j < 16; ++j) { acc0[j] = 0.f; acc1[j] = 0.f; }

        for (int kh = 0; kh < 2; ++kh) {
            __syncthreads();   // protect hs/xs/w1s from previous use
            // stage w1 half: [h][kq] -> w1s[h*17 + kq] (float4 units)
#pragma unroll
            for (int i = 0; i < 8; ++i) {
                int flat4 = i * 256 + t;
                int h = flat4 >> 4, kq = flat4 & 15;
                float4 v = ((const float4*)w1)[h * 32 + kh * 16 + kq];
                ((float4*)w1s)[h * 17 + kq] = v;
            }
            // stage x tile: 64 nodes x 64 k
#pragma unroll
            for (int i = 0; i < 4; ++i) {
                int flat4 = i * 256 + t;
                int n = flat4 >> 4, kq = flat4 & 15;
                int node = base + n; if (node >= n_nodes) node = n_nodes - 1;
                float4 v = ((const float4*)x)[node * 32 + kh * 16 + kq];
                ((float4*)xs)[n * 17 + kq] = v;
            }
            __syncthreads();
            // FMA loop: 16 k4 steps
#pragma unroll
            for (int k4 = 0; k4 < 16; ++k4) {
                float4 wa = ((const float4*)w1s)[lane * 17 + k4];
                float4 wb = ((const float4*)w1s)[(lane + 64) * 17 + k4];
#pragma unroll
                for (int j = 0; j < 16; ++j) {
                    float4 xv = ((const float4*)xs)[(w * 16 + j) * 17 + k4];
                    acc0[j] += wa.x * xv.x + wa.y * xv.y + wa.z * xv.z + wa.w * xv.w;
                    acc1[j] += wb.x * xv.x + wb.y * xv.y + wb.z * xv.z + wb.w * xv.w;
                }
            }
        }
        __syncthreads();   // all waves done reading w1s/xs before hs overwrite
        // tanh -> hs[node][h], padded stride 132
#pragma unroll
        for (int j = 0; j < 16; ++j) {
            int n = w * 16 + j;
            float a0 = acc0[j], a1 = acc1[j];
            float e0 = __expf(-2.f * fabsf(a0));
            float t0 = copysignf((1.f - e0) * __builtin_amdgcn_rcpf(1.f + e0), a0);
            float e1 = __expf(-2.f * fabsf(a1));
            float t1 = copysignf((1.f - e1) * __builtin_amdgcn_rcpf(1.f + e1), a1);
            hs[n * 132 + lane] = t0;
            hs[n * 132 + 64 + lane] = t1;
        }
        __syncthreads();
        // second matmul: thread t -> (o = t&7, rows n = t>>3 and n+32), full K dot
        {
            const int o = t & 7, n = t >> 3;
            float s0 = 0.f, s1 = 0.f;
#pragma unroll 8
            for (int k4 = 0; k4 < 32; ++k4) {
                float4 wv = ((const float4*)w2)[o * 32 + k4];
                float4 h0 = ((const float4*)hs)[n * 33 + k4];
                float4 h1 = ((const float4*)hs)[(n + 32) * 33 + k4];
                s0 += wv.x * h0.x + wv.y * h0.y + wv.z * h0.z + wv.w * h0.w;
                s1 += wv.x * h1.x + wv.y * h1.y + wv.z * h1.z + wv.w * h1.w;
            }
            if (base + n < n_nodes)      scores[(base + n) * 8 + o] = s0;
            if (base + n + 32 < n_nodes) scores[(base + n + 32) * 8 + o] = s1;
        }
    }
}

// ---------------- Phase B: per-graph max and 1/sum(exp) ----------------
__global__ __launch_bounds__(256) void segstat_kernel(
    const float* __restrict__ scores, const int* __restrict__ batch,
    float* __restrict__ gmax, float* __restrict__ ginv, int n_nodes)
{
    __shared__ float red[256];
    __shared__ float gmx[8];
    const int g = blockIdx.x, t = threadIdx.x;
    const int s = lower_bound_i(batch, n_nodes, g);
    const int e = lower_bound_i(batch, n_nodes, g + 1);
    const int o = t & 7, j = t >> 3;

    float m = -INFINITY;
    for (int n = s + j; n < e; n += 32) m = fmaxf(m, scores[n * 8 + o]);
    red[t] = m;
    __syncthreads();
    for (int st = 128; st >= 8; st >>= 1) {
        if (t < st) red[t] = fmaxf(red[t], red[t + st]);
        __syncthreads();
    }
    if (t < 8) gmx[t] = red[t];
    __syncthreads();
    const float gm = gmx[o];
    float sacc = 0.f;
    for (int n = s + j; n < e; n += 32) sacc += __expf(scores[n * 8 + o] - gm);
    __syncthreads();
    red[t] = sacc;
    __syncthreads();
    for (int st = 128; st >= 8; st >>= 1) {
        if (t < st) red[t] += red[t + st];
        __syncthreads();
    }
    if (t < 8) {
        gmax[g * 8 + t] = gmx[t];
        ginv[g * 8 + t] = 1.f / red[t];   // inf for empty graph: never consumed
    }
}

// ---------------- Phase C: out[g][o][f] = sum_n attn[n][o] * x[n][f] ----------------
__global__ __launch_bounds__(256) void out_kernel(
    const float* __restrict__ x, const float* __restrict__ scores,
    const int* __restrict__ batch, const float* __restrict__ gmax,
    const float* __restrict__ ginv, float* __restrict__ out, int n_nodes)
{
    __shared__ __align__(16) float xsl[8 * 128];
    __shared__ __align__(16) float atl[8 * 8];
    __shared__ float gmL[8], giL[8];
    const int g = blockIdx.x, t = threadIdx.x;
    const int s = lower_bound_i(batch, n_nodes, g);
    const int e = lower_bound_i(batch, n_nodes, g + 1);
    if (t < 8) { gmL[t] = gmax[g * 8 + t]; giL[t] = ginv[g * 8 + t]; }
    const int f = t & 127, ob = t >> 7;    // thread covers o in {4*ob..4*ob+3} at feature f
    float a0 = 0.f, a1 = 0.f, a2 = 0.f, a3 = 0.f;

    for (int c = s; c < e; c += 8) {
        const int cnt = min(8, e - c);
        __syncthreads();   // protects prev-iter reads and gmL/giL on first iter
        {
            int row = t >> 5, col4 = t & 31;
            if (row < cnt)
                ((float4*)xsl)[row * 32 + col4] = ((const float4*)x)[(c + row) * 32 + col4];
        }
        if (t < 64) {
            int j = t >> 3, o = t & 7;
            if (j < cnt)
                atl[j * 8 + o] = __expf(scores[(c + j) * 8 + o] - gmL[o]) * giL[o];
        }
        __syncthreads();
        for (int j = 0; j < cnt; ++j) {
            float xv = xsl[j * 128 + f];
            float4 a4 = ((const float4*)atl)[j * 2 + ob];
            a0 += a4.x * xv; a1 += a4.y * xv; a2 += a4.z * xv; a3 += a4.w * xv;
        }
    }
    const int gb = g * 1024 + ob * 512 + f;
    out[gb]       = a0;
    out[gb + 128] = a1;
    out[gb + 256] = a2;
    out[gb + 384] = a3;
}

extern "C" void kernel_launch(void* const* d_in, const int* in_sizes, int n_in,
                              void* d_out, int out_size, void* d_ws, size_t ws_size,
                              hipStream_t stream)
{
    const float* x     = (const float*)d_in[0];
    const int*   batch = (const int*)d_in[1];
    const float* w1    = (const float*)d_in[2];
    const float* w2    = (const float*)d_in[3];
    const int n_nodes  = in_sizes[1];
    float* out = (float*)d_out;

    float* scores = (float*)d_ws;                         // n_nodes*8 floats
    float* gmax   = scores + (size_t)n_nodes * 8;         // GG*8
    float* ginv   = gmax + (size_t)GG * 8;                // GG*8

    const int nbg = (n_nodes + 63) / 64;
    hipLaunchKernelGGL(score_kernel,   dim3(768), dim3(256), 0, stream, x, w1, w2, scores, n_nodes, nbg);
    hipLaunchKernelGGL(segstat_kernel, dim3(GG),  dim3(256), 0, stream, scores, batch, gmax, ginv, n_nodes);
    hipLaunchKernelGGL(out_kernel,     dim3(GG),  dim3(256), 0, stream, x, scores, batch, gmax, ginv, out, n_nodes);
}

// Round 2
// 185.400 us; speedup vs baseline: 5.2382x; 5.2382x over previous
//
#include <hip/hip_runtime.h>
#include <math.h>

#define GG 2000   // num_graphs (reference constant)

__device__ __forceinline__ int lower_bound_i(const int* __restrict__ b, int n, int v) {
    int lo = 0, hi = n;
    while (lo < hi) { int mid = (lo + hi) >> 1; if (b[mid] < v) lo = mid + 1; else hi = mid; }
    return lo;
}

// ---------------- Phase A: scores[n][o] = tanh(x@w1^T)@w2^T ----------------
// Block = 256 thr (4 waves). Per group: 32 nodes. Wave w owns nodes w*8..w*8+7.
// Lane l accumulates hidden dims l and l+64 -> 16 fp32 accs/thread (no spill).
// K processed in 2 halves of 64 staged in LDS; w2 read direct from global (L1-hot).
// LDS: w1h 128x[17 f4] = 34816 B + xh region 4224 floats = 16896 B -> 51712 B -> 3 blocks/CU.
__global__ __launch_bounds__(256, 3) void score_kernel(
    const float* __restrict__ x, const float* __restrict__ w1,
    const float* __restrict__ w2, float* __restrict__ scores,
    int n_nodes, int nbg)
{
    __shared__ __align__(16) float lds[12928];
    float* w1h = lds;          // [128 h][17 f4] (pad f4 -> conflict-free b128 reads)
    float* xh  = lds + 8704;   // xs: [32 n][16 f4] (8192 B)  ALIASED BY  hs: [32 n][132 f] (16896 B)

    const int t = threadIdx.x;
    const int lane = t & 63;
    const int w = t >> 6;

    for (int bg = blockIdx.x; bg < nbg; bg += gridDim.x) {
        const int base = bg * 32;
        float acc0[8], acc1[8];
#pragma unroll
        for (int j = 0; j < 8; ++j) { acc0[j] = 0.f; acc1[j] = 0.f; }

        for (int kh = 0; kh < 2; ++kh) {
            __syncthreads();   // region free: prev FMA reads / prev-iter hs reads done
            // stage w1 K-half: 2048 f4, 8 per thread
#pragma unroll
            for (int i = 0; i < 8; ++i) {
                int f4 = i * 256 + t;
                int h = f4 >> 4, kq = f4 & 15;
                float4 v = ((const float4*)w1)[h * 32 + kh * 16 + kq];
                ((float4*)w1h)[h * 17 + kq] = v;
            }
            // stage x tile K-half: 512 f4, 2 per thread (unpadded: reads are broadcasts)
#pragma unroll
            for (int i = 0; i < 2; ++i) {
                int f4 = i * 256 + t;
                int n = f4 >> 4, kq = f4 & 15;
                int node = base + n; if (node >= n_nodes) node = n_nodes - 1;
                float4 v = ((const float4*)x)[node * 32 + kh * 16 + kq];
                ((float4*)xh)[n * 16 + kq] = v;
            }
            __syncthreads();
            // FMA loop: 16 k4 steps, 64 FMA-instr each
#pragma unroll 4
            for (int k4 = 0; k4 < 16; ++k4) {
                float4 wa = ((const float4*)w1h)[lane * 17 + k4];
                float4 wb = ((const float4*)w1h)[(lane + 64) * 17 + k4];
#pragma unroll
                for (int j = 0; j < 8; ++j) {
                    float4 xv = ((const float4*)xh)[(w * 8 + j) * 16 + k4];  // wave-uniform broadcast
                    acc0[j] = fmaf(wa.x, xv.x, acc0[j]);
                    acc0[j] = fmaf(wa.y, xv.y, acc0[j]);
                    acc0[j] = fmaf(wa.z, xv.z, acc0[j]);
                    acc0[j] = fmaf(wa.w, xv.w, acc0[j]);
                    acc1[j] = fmaf(wb.x, xv.x, acc1[j]);
                    acc1[j] = fmaf(wb.y, xv.y, acc1[j]);
                    acc1[j] = fmaf(wb.z, xv.z, acc1[j]);
                    acc1[j] = fmaf(wb.w, xv.w, acc1[j]);
                }
            }
        }
        __syncthreads();   // all waves done reading xh as x-tile before hs overwrite
        // tanh -> hs[node][h], stride 132 floats
#pragma unroll
        for (int j = 0; j < 8; ++j) {
            int n = w * 8 + j;
            float a0 = acc0[j], a1 = acc1[j];
            float e0 = __expf(-2.f * fabsf(a0));
            float t0 = copysignf((1.f - e0) * __builtin_amdgcn_rcpf(1.f + e0), a0);
            float e1 = __expf(-2.f * fabsf(a1));
            float t1 = copysignf((1.f - e1) * __builtin_amdgcn_rcpf(1.f + e1), a1);
            xh[n * 132 + lane] = t0;
            xh[n * 132 + 64 + lane] = t1;
        }
        __syncthreads();
        // second matmul: per wave: o = lane>>3, node = w*8 + (lane&7); w2 from global (L1-hot)
        {
            const int o = lane >> 3;
            const int n = w * 8 + (lane & 7);
            float s = 0.f;
#pragma unroll 8
            for (int k4 = 0; k4 < 32; ++k4) {
                float4 wv = ((const float4*)w2)[o * 32 + k4];
                float4 hv = ((const float4*)xh)[n * 33 + k4];
                s = fmaf(wv.x, hv.x, s);
                s = fmaf(wv.y, hv.y, s);
                s = fmaf(wv.z, hv.z, s);
                s = fmaf(wv.w, hv.w, s);
            }
            if (base + n < n_nodes) scores[(base + n) * 8 + o] = s;
        }
    }
}

// ---------------- Phase B: per-graph max and 1/sum(exp) ----------------
__global__ __launch_bounds__(256) void segstat_kernel(
    const float* __restrict__ scores, const int* __restrict__ batch,
    float* __restrict__ gmax, float* __restrict__ ginv, int n_nodes)
{
    __shared__ float red[256];
    __shared__ float gmx[8];
    const int g = blockIdx.x, t = threadIdx.x;
    const int s = lower_bound_i(batch, n_nodes, g);
    const int e = lower_bound_i(batch, n_nodes, g + 1);
    const int o = t & 7, j = t >> 3;

    float m = -INFINITY;
    for (int n = s + j; n < e; n += 32) m = fmaxf(m, scores[n * 8 + o]);
    red[t] = m;
    __syncthreads();
    for (int st = 128; st >= 8; st >>= 1) {
        if (t < st) red[t] = fmaxf(red[t], red[t + st]);
        __syncthreads();
    }
    if (t < 8) gmx[t] = red[t];
    __syncthreads();
    const float gm = gmx[o];
    float sacc = 0.f;
    for (int n = s + j; n < e; n += 32) sacc += __expf(scores[n * 8 + o] - gm);
    __syncthreads();
    red[t] = sacc;
    __syncthreads();
    for (int st = 128; st >= 8; st >>= 1) {
        if (t < st) red[t] += red[t + st];
        __syncthreads();
    }
    if (t < 8) {
        gmax[g * 8 + t] = gmx[t];
        ginv[g * 8 + t] = 1.f / red[t];   // inf for empty graph: never consumed
    }
}

// ---------------- Phase C: out[g][o][f] = sum_n attn[n][o] * x[n][f] ----------------
__global__ __launch_bounds__(256) void out_kernel(
    const float* __restrict__ x, const float* __restrict__ scores,
    const int* __restrict__ batch, const float* __restrict__ gmax,
    const float* __restrict__ ginv, float* __restrict__ out, int n_nodes)
{
    __shared__ __align__(16) float xsl[8 * 128];
    __shared__ __align__(16) float atl[8 * 8];
    __shared__ float gmL[8], giL[8];
    const int g = blockIdx.x, t = threadIdx.x;
    const int s = lower_bound_i(batch, n_nodes, g);
    const int e = lower_bound_i(batch, n_nodes, g + 1);
    if (t < 8) { gmL[t] = gmax[g * 8 + t]; giL[t] = ginv[g * 8 + t]; }
    const int f = t & 127, ob = t >> 7;    // thread covers o in {4*ob..4*ob+3} at feature f
    float a0 = 0.f, a1 = 0.f, a2 = 0.f, a3 = 0.f;

    for (int c = s; c < e; c += 8) {
        const int cnt = min(8, e - c);
        __syncthreads();   // protects prev-iter reads and gmL/giL on first iter
        {
            int row = t >> 5, col4 = t & 31;
            if (row < cnt)
                ((float4*)xsl)[row * 32 + col4] = ((const float4*)x)[(c + row) * 32 + col4];
        }
        if (t < 64) {
            int j = t >> 3, o = t & 7;
            if (j < cnt)
                atl[j * 8 + o] = __expf(scores[(c + j) * 8 + o] - gmL[o]) * giL[o];
        }
        __syncthreads();
        for (int j = 0; j < cnt; ++j) {
            float xv = xsl[j * 128 + f];
            float4 a4 = ((const float4*)atl)[j * 2 + ob];
            a0 += a4.x * xv; a1 += a4.y * xv; a2 += a4.z * xv; a3 += a4.w * xv;
        }
    }
    const int gb = g * 1024 + ob * 512 + f;
    out[gb]       = a0;
    out[gb + 128] = a1;
    out[gb + 256] = a2;
    out[gb + 384] = a3;
}

extern "C" void kernel_launch(void* const* d_in, const int* in_sizes, int n_in,
                              void* d_out, int out_size, void* d_ws, size_t ws_size,
                              hipStream_t stream)
{
    const float* x     = (const float*)d_in[0];
    const int*   batch = (const int*)d_in[1];
    const float* w1    = (const float*)d_in[2];
    const float* w2    = (const float*)d_in[3];
    const int n_nodes  = in_sizes[1];
    float* out = (float*)d_out;

    float* scores = (float*)d_ws;                         // n_nodes*8 floats
    float* gmax   = scores + (size_t)n_nodes * 8;         // GG*8
    float* ginv   = gmax + (size_t)GG * 8;                // GG*8

    const int nbg = (n_nodes + 31) / 32;
    hipLaunchKernelGGL(score_kernel,   dim3(768), dim3(256), 0, stream, x, w1, w2, scores, n_nodes, nbg);
    hipLaunchKernelGGL(segstat_kernel, dim3(GG),  dim3(256), 0, stream, scores, batch, gmax, ginv, n_nodes);
    hipLaunchKernelGGL(out_kernel,     dim3(GG),  dim3(256), 0, stream, x, scores, batch, gmax, ginv, out, n_nodes);
}

// Round 3
// 72.964 us; speedup vs baseline: 13.3102x; 2.5410x over previous
//
#include <hip/hip_runtime.h>
#include <math.h>

#define GG 2000   // num_graphs (reference constant)

typedef short bf16x8 __attribute__((ext_vector_type(8)));
typedef float f32x4  __attribute__((ext_vector_type(4)));

__device__ __forceinline__ unsigned short f2b(float f) {
    unsigned int u = __float_as_uint(f);
    u += 0x7FFFu + ((u >> 16) & 1u);          // round-to-nearest-even
    return (unsigned short)(u >> 16);
}

__device__ __forceinline__ int lower_bound_i(const int* __restrict__ b, int n, int v) {
    int lo = 0, hi = n;
    while (lo < hi) { int mid = (lo + hi) >> 1; if (b[mid] < v) lo = mid + 1; else hi = mid; }
    return lo;
}

// ---------------- Phase A: scores = tanh(x@w1^T)@w2^T via bf16 MFMA ----------------
// Block 256 thr = 4 waves; tile = 128 nodes; wave w owns nodes w*32..w*32+31.
// GEMM1: A(x) direct-from-global fp32->bf16 regs; B(w1) bf16 LDS (swizzled).
// GEMM2: A(h=tanh) bf16 LDS (wave-private rows, barrier-free); B(w2) in regs, O padded to 16.
__global__ __launch_bounds__(256, 2) void score_kernel(
    const float* __restrict__ x, const float* __restrict__ w1,
    const float* __restrict__ w2, float* __restrict__ scores,
    int n_nodes, int ngrp)
{
    __shared__ __align__(16) unsigned short w1b[16384]; // [128 hid][128 k] bf16, slot^=(row&7)
    __shared__ __align__(16) unsigned short hb[16384];  // [128 m][128 n] bf16, slot^=(row&7)

    const int t   = threadIdx.x;
    const int lane = t & 63;
    const int w   = t >> 6;
    const int l15 = lane & 15;
    const int lg  = lane >> 4;          // 0..3  (k-group)

    // ---- stage w1 -> bf16 LDS once (coalesced float4 reads) ----
#pragma unroll
    for (int i = 0; i < 16; ++i) {
        int f4 = i * 256 + t;                  // 4096 float4 total
        int row = f4 >> 5, q = f4 & 31;        // 32 float4 per row
        float4 v = ((const float4*)w1)[f4];
        ushort4 p;
        p.x = f2b(v.x); p.y = f2b(v.y); p.z = f2b(v.z); p.w = f2b(v.w);
        int slot = (q >> 1) ^ (row & 7);
        *(ushort4*)((char*)w1b + row * 256 + slot * 16 + (q & 1) * 8) = p;
    }

    // ---- w2 b-frags in registers: lane l -> col o=l15 (rows 8..15 zero) ----
    bf16x8 w2f[4];
    {
        const int o = l15;
#pragma unroll
        for (int ks = 0; ks < 4; ++ks) {
            float tmp[8];
            if (o < 8) {
                float4 u0 = ((const float4*)w2)[o * 32 + ks * 8 + lg * 2];
                float4 u1 = ((const float4*)w2)[o * 32 + ks * 8 + lg * 2 + 1];
                tmp[0]=u0.x; tmp[1]=u0.y; tmp[2]=u0.z; tmp[3]=u0.w;
                tmp[4]=u1.x; tmp[5]=u1.y; tmp[6]=u1.z; tmp[7]=u1.w;
            } else {
#pragma unroll
                for (int i = 0; i < 8; ++i) tmp[i] = 0.f;
            }
            bf16x8 r;
#pragma unroll
            for (int i = 0; i < 8; ++i) r[i] = (short)f2b(tmp[i]);
            w2f[ks] = r;
        }
    }
    __syncthreads();

    for (int g = blockIdx.x; g < ngrp; g += gridDim.x) {
        const int base = g * 128;

        // ---- GEMM1: acc[mt][nt] = x-tile @ w1^T ----
        f32x4 acc[2][8];
#pragma unroll
        for (int mt = 0; mt < 2; ++mt)
#pragma unroll
            for (int nt = 0; nt < 8; ++nt)
#pragma unroll
                for (int r = 0; r < 4; ++r) acc[mt][nt][r] = 0.f;

#pragma unroll
        for (int ks = 0; ks < 4; ++ks) {
            bf16x8 bf[8];
#pragma unroll
            for (int nt = 0; nt < 8; ++nt) {
                int row = nt * 16 + l15;
                int slot = (ks * 4 + lg) ^ (row & 7);
                bf[nt] = *(bf16x8*)((char*)w1b + row * 256 + slot * 16);
            }
#pragma unroll
            for (int mt = 0; mt < 2; ++mt) {
                int node = base + w * 32 + mt * 16 + l15;
                if (node >= n_nodes) node = n_nodes - 1;
                const float4* xp = (const float4*)x + (size_t)node * 32 + ks * 8 + lg * 2;
                float4 u0 = xp[0], u1 = xp[1];
                float tmp[8] = {u0.x,u0.y,u0.z,u0.w,u1.x,u1.y,u1.z,u1.w};
                bf16x8 af;
#pragma unroll
                for (int i = 0; i < 8; ++i) af[i] = (short)f2b(tmp[i]);
#pragma unroll
                for (int nt = 0; nt < 8; ++nt)
                    acc[mt][nt] = __builtin_amdgcn_mfma_f32_16x16x32_bf16(af, bf[nt], acc[mt][nt], 0, 0, 0);
            }
        }

        // ---- tanh -> hb (wave-private rows; LDS in-order per wave => no barrier) ----
#pragma unroll
        for (int mt = 0; mt < 2; ++mt)
#pragma unroll
            for (int nt = 0; nt < 8; ++nt)
#pragma unroll
                for (int r = 0; r < 4; ++r) {
                    float a = acc[mt][nt][r];
                    float e = __expf(-2.f * fabsf(a));
                    float th = copysignf((1.f - e) * __builtin_amdgcn_rcpf(1.f + e), a);
                    int m = w * 32 + mt * 16 + lg * 4 + r;
                    int n = nt * 16 + l15;
                    int slot = (n >> 3) ^ (m & 7);
                    *(unsigned short*)((char*)hb + m * 256 + slot * 16 + (n & 7) * 2) = f2b(th);
                }

        // ---- GEMM2: scores-tile = h @ w2^T (cols 8..15 are padding) ----
        f32x4 acc2[2];
#pragma unroll
        for (int mt = 0; mt < 2; ++mt)
#pragma unroll
            for (int r = 0; r < 4; ++r) acc2[mt][r] = 0.f;

#pragma unroll
        for (int ks = 0; ks < 4; ++ks)
#pragma unroll
            for (int mt = 0; mt < 2; ++mt) {
                int m = w * 32 + mt * 16 + l15;
                int slot = (ks * 4 + lg) ^ (m & 7);
                bf16x8 hf = *(bf16x8*)((char*)hb + m * 256 + slot * 16);
                acc2[mt] = __builtin_amdgcn_mfma_f32_16x16x32_bf16(hf, w2f[ks], acc2[mt], 0, 0, 0);
            }

        // ---- store scores (col o = l15 < 8 valid) ----
        if (l15 < 8) {
#pragma unroll
            for (int mt = 0; mt < 2; ++mt)
#pragma unroll
                for (int r = 0; r < 4; ++r) {
                    int node = base + w * 32 + mt * 16 + lg * 4 + r;
                    if (node < n_nodes) scores[node * 8 + l15] = acc2[mt][r];
                }
        }
        // hb rows are wave-private and w1b is read-only: no __syncthreads needed.
    }
}

// ---------------- Phase B: per-graph max and 1/sum(exp) ----------------
__global__ __launch_bounds__(256) void segstat_kernel(
    const float* __restrict__ scores, const int* __restrict__ batch,
    float* __restrict__ gmax, float* __restrict__ ginv, int n_nodes)
{
    __shared__ float red[256];
    __shared__ float gmx[8];
    const int g = blockIdx.x, t = threadIdx.x;
    const int s = lower_bound_i(batch, n_nodes, g);
    const int e = lower_bound_i(batch, n_nodes, g + 1);
    const int o = t & 7, j = t >> 3;

    float m = -INFINITY;
    for (int n = s + j; n < e; n += 32) m = fmaxf(m, scores[n * 8 + o]);
    red[t] = m;
    __syncthreads();
    for (int st = 128; st >= 8; st >>= 1) {
        if (t < st) red[t] = fmaxf(red[t], red[t + st]);
        __syncthreads();
    }
    if (t < 8) gmx[t] = red[t];
    __syncthreads();
    const float gm = gmx[o];
    float sacc = 0.f;
    for (int n = s + j; n < e; n += 32) sacc += __expf(scores[n * 8 + o] - gm);
    __syncthreads();
    red[t] = sacc;
    __syncthreads();
    for (int st = 128; st >= 8; st >>= 1) {
        if (t < st) red[t] += red[t + st];
        __syncthreads();
    }
    if (t < 8) {
        gmax[g * 8 + t] = gmx[t];
        ginv[g * 8 + t] = 1.f / red[t];   // inf for empty graph: never consumed
    }
}

// ---------------- Phase C: out[g][o][f] = sum_n attn[n][o] * x[n][f] ----------------
__global__ __launch_bounds__(256) void out_kernel(
    const float* __restrict__ x, const float* __restrict__ scores,
    const int* __restrict__ batch, const float* __restrict__ gmax,
    const float* __restrict__ ginv, float* __restrict__ out, int n_nodes)
{
    __shared__ __align__(16) float xsl[8 * 128];
    __shared__ __align__(16) float atl[8 * 8];
    __shared__ float gmL[8], giL[8];
    const int g = blockIdx.x, t = threadIdx.x;
    const int s = lower_bound_i(batch, n_nodes, g);
    const int e = lower_bound_i(batch, n_nodes, g + 1);
    if (t < 8) { gmL[t] = gmax[g * 8 + t]; giL[t] = ginv[g * 8 + t]; }
    const int f = t & 127, ob = t >> 7;
    float a0 = 0.f, a1 = 0.f, a2 = 0.f, a3 = 0.f;

    for (int c = s; c < e; c += 8) {
        const int cnt = min(8, e - c);
        __syncthreads();
        {
            int row = t >> 5, col4 = t & 31;
            if (row < cnt)
                ((float4*)xsl)[row * 32 + col4] = ((const float4*)x)[(c + row) * 32 + col4];
        }
        if (t < 64) {
            int j = t >> 3, o = t & 7;
            if (j < cnt)
                atl[j * 8 + o] = __expf(scores[(c + j) * 8 + o] - gmL[o]) * giL[o];
        }
        __syncthreads();
        for (int j = 0; j < cnt; ++j) {
            float xv = xsl[j * 128 + f];
            float4 a4 = ((const float4*)atl)[j * 2 + ob];
            a0 += a4.x * xv; a1 += a4.y * xv; a2 += a4.z * xv; a3 += a4.w * xv;
        }
    }
    const int gb = g * 1024 + ob * 512 + f;
    out[gb]       = a0;
    out[gb + 128] = a1;
    out[gb + 256] = a2;
    out[gb + 384] = a3;
}

extern "C" void kernel_launch(void* const* d_in, const int* in_sizes, int n_in,
                              void* d_out, int out_size, void* d_ws, size_t ws_size,
                              hipStream_t stream)
{
    const float* x     = (const float*)d_in[0];
    const int*   batch = (const int*)d_in[1];
    const float* w1    = (const float*)d_in[2];
    const float* w2    = (const float*)d_in[3];
    const int n_nodes  = in_sizes[1];
    float* out = (float*)d_out;

    float* scores = (float*)d_ws;                         // n_nodes*8 floats
    float* gmax   = scores + (size_t)n_nodes * 8;         // GG*8
    float* ginv   = gmax + (size_t)GG * 8;                // GG*8

    const int ngrp = (n_nodes + 127) / 128;
    hipLaunchKernelGGL(score_kernel,   dim3(512), dim3(256), 0, stream, x, w1, w2, scores, n_nodes, ngrp);
    hipLaunchKernelGGL(segstat_kernel, dim3(GG),  dim3(256), 0, stream, scores, batch, gmax, ginv, n_nodes);
    hipLaunchKernelGGL(out_kernel,     dim3(GG),  dim3(256), 0, stream, x, scores, batch, gmax, ginv, out, n_nodes);
}